// Round 8
// baseline (360.643 us; speedup 1.0000x reference)
//
#include <hip/hip_runtime.h>

#define NN 50000
#define NE 800000
#define HH 128
#define BN_EPS 1e-5f
#define SCAN_NB ((NN + 255) / 256)   // 196 blocks of 256

typedef unsigned short u16;
typedef unsigned int u32;
typedef short bf16x8 __attribute__((ext_vector_type(8)));
typedef float f32x4 __attribute__((ext_vector_type(4)));

static __device__ __forceinline__ float bf2f(u16 u){
  union { u32 i; float f; } v; v.i = ((u32)u) << 16; return v.f;
}
static __device__ __forceinline__ u16 f2bf(float f){
  union { float f; u32 i; } v; v.f = f;
  u32 x = v.i;
  return (u16)((x + 0x7fffu + ((x >> 16) & 1u)) >> 16);
}
static __device__ __forceinline__ float sigm(float x){
  return 1.f / (1.f + __expf(-x));
}
static __device__ __forceinline__ float tanh_fast(float x){
  return 1.f - 2.f / (1.f + __expf(2.f * x));
}

// ---------------- edge preprocessing ----------------

__global__ void hist_kernel(const int* __restrict__ dst, int* __restrict__ counts, int E){
  int e = blockIdx.x * blockDim.x + threadIdx.x;
  if (e < E) atomicAdd(&counts[dst[e]], 1);
}

// ---- parallel 3-phase exclusive scan ----

__global__ __launch_bounds__(256) void scan_bsum(
    const int* __restrict__ counts, int* __restrict__ bsums, int n){
  int i = blockIdx.x * 256 + threadIdx.x;
  int v = (i < n) ? counts[i] : 0;
#pragma unroll
  for (int off = 1; off < 64; off <<= 1) v += __shfl_xor(v, off);
  __shared__ int ws[4];
  if ((threadIdx.x & 63) == 0) ws[threadIdx.x >> 6] = v;
  __syncthreads();
  if (threadIdx.x == 0) bsums[blockIdx.x] = ws[0] + ws[1] + ws[2] + ws[3];
}

__global__ __launch_bounds__(256) void scan_tops(int* __restrict__ bsums, int nb){
  __shared__ int sh[256];
  int t = threadIdx.x;
  int v = (t < nb) ? bsums[t] : 0;
  sh[t] = v;
  __syncthreads();
  for (int off = 1; off < 256; off <<= 1){
    int u = (t >= off) ? sh[t - off] : 0;
    __syncthreads();
    sh[t] += u;
    __syncthreads();
  }
  if (t < nb) bsums[t] = sh[t] - v;   // exclusive
}

__global__ __launch_bounds__(256) void scan_final(
    const int* __restrict__ counts, const int* __restrict__ bsums,
    int* __restrict__ offs, int* __restrict__ cursor, int n){
  __shared__ int sh[256];
  int t = threadIdx.x;
  int i = blockIdx.x * 256 + t;
  int v = (i < n) ? counts[i] : 0;
  sh[t] = v;
  __syncthreads();
  for (int off = 1; off < 256; off <<= 1){
    int u = (t >= off) ? sh[t - off] : 0;
    __syncthreads();
    sh[t] += u;
    __syncthreads();
  }
  int excl = sh[t] - v + bsums[blockIdx.x];
  if (i < n){ offs[i] = excl; cursor[i] = excl; }
}

// scatter edges into dst-sorted buckets; pack (src, weight) as int2
__global__ void scatter_kernel(const int* __restrict__ src, const int* __restrict__ dst,
                               const float* __restrict__ w, int* __restrict__ cursor,
                               int2* __restrict__ esw, int E){
  int e = blockIdx.x * blockDim.x + threadIdx.x;
  if (e < E){
    int d = dst[e];
    int pos = atomicAdd(&cursor[d], 1);
    esw[pos] = make_int2(src[e], __float_as_int(w[e]));
  }
}

// ---------------- pack weights to bf16 B^T layouts + bias sums ----------------
// wcat is stored FRAGMENT-SEQUENTIAL: [ntile(32)][kk(8)][lane(64)][e(8)] where
// n = ntile*16 + (lane&15), k = kk*32 + (lane>>4)*8 + e -> one bf16x8 wave-load
// per MFMA B fragment, perfectly lane-linear.
// Also zeroes counts[] (replaces a separate memset dispatch).
__global__ void prep_pack(const float* __restrict__ x2hw, const float* __restrict__ h2hw,
                          const float* __restrict__ x2hb, const float* __restrict__ h2hb,
                          const float* __restrict__ gcnw,
                          u16* __restrict__ wcat, u16* __restrict__ wgcn,
                          float* __restrict__ bsum, int* __restrict__ counts){
  int i = blockIdx.x * blockDim.x + threadIdx.x;   // 131072 threads
  int n = i >> 8, k = i & 255;
  float v = (k < 128) ? x2hw[n * 128 + k] : h2hw[n * 128 + (k - 128)];
  int nt = n >> 4, lc = n & 15;
  int kk = k >> 5, lq = (k >> 3) & 3, e = k & 7;
  wcat[(((nt * 8 + kk) * 64) + lq * 16 + lc) * 8 + e] = f2bf(v);
  if (i < 16384){
    int nn = i >> 7, kx = i & 127;
    wgcn[i] = f2bf(gcnw[kx * 128 + nn]);   // transpose [k][n] -> [n][k]
  }
  if (i < 512) bsum[i] = x2hb[i] + h2hb[i];
  if (i < NN) counts[i] = 0;
}

// ---------------- support = x @ gcn_weight via MFMA, global-direct ----------------
__global__ __launch_bounds__(256) void support_mfma(
    const float* __restrict__ x, const u16* __restrict__ wgcn,
    u16* __restrict__ support, int N){
  int tid = threadIdx.x;
  int wave = tid >> 6, lane = tid & 63;
  int c = lane & 15, q = lane >> 4;
  int row0 = blockIdx.x * 64 + wave * 16;
  int arow = row0 + c; if (arow > N - 1) arow = N - 1;   // clamp OOB reads
  f32x4 acc[8];
#pragma unroll
  for (int t = 0; t < 8; t++) acc[t] = (f32x4){0.f, 0.f, 0.f, 0.f};

  const u16* wp = wgcn + (size_t)c * 128 + q * 8;
#pragma unroll
  for (int k0 = 0; k0 < 128; k0 += 32){
    const float* ap = x + (size_t)arow * 128 + k0 + q * 8;
    float4 f0 = *(const float4*)ap;
    float4 f1 = *(const float4*)(ap + 4);
    u16 tmp[8] = {f2bf(f0.x), f2bf(f0.y), f2bf(f0.z), f2bf(f0.w),
                  f2bf(f1.x), f2bf(f1.y), f2bf(f1.z), f2bf(f1.w)};
    bf16x8 afrag = *(bf16x8*)tmp;
#pragma unroll
    for (int t = 0; t < 8; t++){
      bf16x8 bfrag = *(const bf16x8*)(wp + (size_t)t * 16 * 128 + k0);
      acc[t] = __builtin_amdgcn_mfma_f32_16x16x32_bf16(afrag, bfrag, acc[t], 0, 0, 0);
    }
  }
#pragma unroll
  for (int t = 0; t < 8; t++){
#pragma unroll
    for (int j = 0; j < 4; j++){
      int r = row0 + q * 4 + j;
      if (r < N) support[(size_t)r * 128 + t * 16 + c] = f2bf(acc[t][j]);
    }
  }
}

// ---------------- CSR aggregate + relu + bias + BN -> h_bn (bf16) ----------------
// v3: edge metadata read via WAVE-UNIFORM loads (start+e is uniform per wave ->
// compiler emits scalar-cache loads), removing all __shfl broadcasts and the
// 64-edge staging loop. 8 independent gathers in flight per step; fmaf chain
// order identical to the serial loop (bit-exact).
__global__ __launch_bounds__(256) void agg_bn3(
    const u16* __restrict__ support, const int2* __restrict__ esw,
    const int* __restrict__ offs, const int* __restrict__ counts,
    const float* __restrict__ bias, const float* __restrict__ gamma,
    const float* __restrict__ beta, const float* __restrict__ mean,
    const float* __restrict__ var, const float* __restrict__ hx,
    u16* __restrict__ hbn, u16* __restrict__ hxb, int N){
  int wid = blockIdx.x * 4 + (threadIdx.x >> 6);
  int lane = threadIdx.x & 63;
  if (wid >= N) return;
  int c = lane * 2;
  // hx row -> bf16 (independent of aggregation; issues early)
  float2 hv = *(const float2*)(hx + (size_t)wid * HH + c);
  int start = offs[wid];
  int deg   = counts[wid];
  float a0 = 0.f, a1 = 0.f;
  int e = 0;
  for (; e + 8 <= deg; e += 8){
    int2 ev[8]; u32 u[8];
#pragma unroll
    for (int k = 0; k < 8; k++) ev[k] = esw[start + e + k];   // uniform -> s_load
#pragma unroll
    for (int k = 0; k < 8; k++)
      u[k] = *(const u32*)(support + (size_t)ev[k].x * HH + c);
#pragma unroll
    for (int k = 0; k < 8; k++){
      float g = __int_as_float(ev[k].y);
      a0 = fmaf(g, bf2f((u16)(u[k] & 0xffffu)), a0);
      a1 = fmaf(g, bf2f((u16)(u[k] >> 16)), a1);
    }
  }
  for (; e + 4 <= deg; e += 4){
    int2 ev[4]; u32 u[4];
#pragma unroll
    for (int k = 0; k < 4; k++) ev[k] = esw[start + e + k];
#pragma unroll
    for (int k = 0; k < 4; k++)
      u[k] = *(const u32*)(support + (size_t)ev[k].x * HH + c);
#pragma unroll
    for (int k = 0; k < 4; k++){
      float g = __int_as_float(ev[k].y);
      a0 = fmaf(g, bf2f((u16)(u[k] & 0xffffu)), a0);
      a1 = fmaf(g, bf2f((u16)(u[k] >> 16)), a1);
    }
  }
  for (; e < deg; e++){
    int2 ev = esw[start + e];
    float g = __int_as_float(ev.y);
    u32 ui = *(const u32*)(support + (size_t)ev.x * HH + c);
    a0 = fmaf(g, bf2f((u16)(ui & 0xffffu)), a0);
    a1 = fmaf(g, bf2f((u16)(ui >> 16)), a1);
  }
  float h0 = fmaxf(a0, 0.f) + bias[c];
  float h1 = fmaxf(a1, 0.f) + bias[c + 1];
  float s0 = gamma[c]     * rsqrtf(var[c]     + BN_EPS);
  float s1 = gamma[c + 1] * rsqrtf(var[c + 1] + BN_EPS);
  float r0 = (h0 - mean[c])     * s0 + beta[c];
  float r1 = (h1 - mean[c + 1]) * s1 + beta[c + 1];
  u32 pack = (u32)f2bf(r0) | ((u32)f2bf(r1) << 16);
  *(u32*)(hbn + (size_t)wid * HH + c) = pack;
  u32 hp = (u32)f2bf(hv.x) | ((u32)f2bf(hv.y) << 16);
  *(u32*)(hxb + (size_t)wid * HH + c) = hp;
}

// ---------------- gates GEMM v6: B in regs, k-split wave pairs, A prefetch ----------------
// grid = 512 (2 blocks/CU; LDS 2x64KB = 128KB <= 160KB, VGPR 64 -> fits):
// one block's __syncthreads stalls hide under the co-resident block's
// MFMA/epilogue. (Round-7 counters: grid 256 = 1 block/CU pinned occupancy
// at 38% and left every barrier exposed.)
__global__ __launch_bounds__(1024, 1) void gates_mfma6(
    const u16* __restrict__ hbn, const u16* __restrict__ hxb,
    const u16* __restrict__ wcat, const float* __restrict__ bsum,
    const float* __restrict__ cx, float* __restrict__ out, int N){
  __shared__ float lbuf[2][8][16][64];           // 64 KB, [buf][cw][g*4+j][lane]
  int tid = threadIdx.x;
  int wave = tid >> 6, lane = tid & 63;
  int c = lane & 15, q = lane >> 4;
  int cw = wave & 7, kh = wave >> 3;
  int hloc = cw * 16 + c;                        // h in [0,128)

  // resident B: 4 gates x this wave's k-half (4 kk steps) = 64 VGPR
  const bf16x8* wsrc = (const bf16x8*)wcat;
  bf16x8 btile[4][4];
#pragma unroll
  for (int g = 0; g < 4; g++)
#pragma unroll
    for (int kk = 0; kk < 4; kk++)
      btile[g][kk] = wsrc[((size_t)((g * 8 + cw) * 8) + kh * 4 + kk) * 64 + lane];

  float bi = 0.f, bf_ = 0.f, bg = 0.f, bo = 0.f;
  if (kh == 0){
    bi  = bsum[hloc];
    bf_ = bsum[128 + hloc];
    bg  = bsum[256 + hloc];
    bo  = bsum[384 + hloc];
  }
  const u16* abuf = kh ? hxb : hbn;              // each wave reads ONE A matrix
  const size_t NH = (size_t)N * HH;
  const int nchunk = N >> 4;                     // 3125 (N = 50000 = 3125*16)
  int p = 0;
  int chunk = blockIdx.x;

  // preload first chunk's A fragments
  bf16x8 a_cur[4];
  if (chunk < nchunk){
    const u16* ap = abuf + (size_t)((chunk << 4) + c) * 128 + q * 8;
#pragma unroll
    for (int kk = 0; kk < 4; kk++) a_cur[kk] = *(const bf16x8*)(ap + kk * 32);
  }

  for (; chunk < nchunk; chunk += gridDim.x){
    int row0 = chunk << 4;
    // issue next chunk's A loads NOW (in flight across MFMA+barrier+epilogue)
    int nxt = chunk + gridDim.x;
    int prow = (nxt < nchunk) ? (nxt << 4) : 0;  // clamp: loads valid, unused
    const u16* pnp = abuf + (size_t)(prow + c) * 128 + q * 8;
    bf16x8 a_nxt[4];
#pragma unroll
    for (int kk = 0; kk < 4; kk++) a_nxt[kk] = *(const bf16x8*)(pnp + kk * 32);
    // issue this chunk's cx loads early (kh=0 only; used after the barrier)
    float cxv[4];
    if (kh == 0){
#pragma unroll
      for (int j = 0; j < 4; j++)
        cxv[j] = cx[(size_t)(row0 + q * 4 + j) * HH + hloc];
    }

    f32x4 acc[4];
#pragma unroll
    for (int g = 0; g < 4; g++) acc[g] = (f32x4){0.f, 0.f, 0.f, 0.f};
#pragma unroll
    for (int kk = 0; kk < 4; kk++){
#pragma unroll
      for (int g = 0; g < 4; g++)
        acc[g] = __builtin_amdgcn_mfma_f32_16x16x32_bf16(a_cur[kk], btile[g][kk], acc[g], 0, 0, 0);
    }
    if (kh == 1){
#pragma unroll
      for (int g = 0; g < 4; g++)
#pragma unroll
        for (int j = 0; j < 4; j++)
          lbuf[p][cw][g * 4 + j][lane] = acc[g][j];
    }
    __syncthreads();
    if (kh == 0){
#pragma unroll
      for (int j = 0; j < 4; j++){
        int r = row0 + q * 4 + j;
        float gi = acc[0][j] + lbuf[p][cw][0 + j][lane]  + bi;
        float gf = acc[1][j] + lbuf[p][cw][4 + j][lane]  + bf_;
        float gg = acc[2][j] + lbuf[p][cw][8 + j][lane]  + bg;
        float go = acc[3][j] + lbuf[p][cw][12 + j][lane] + bo;
        float is = sigm(gi), fs = sigm(gf), gt = tanh_fast(gg), os = sigm(go);
        float cyv = cxv[j] * fs + is * gt;
        out[(size_t)r * HH + hloc]      = os * tanh_fast(cyv);
        out[NH + (size_t)r * HH + hloc] = cyv;
      }
    }
#pragma unroll
    for (int kk = 0; kk < 4; kk++) a_cur[kk] = a_nxt[kk];
    p ^= 1;
  }
}

// ---------------- launch ----------------

extern "C" void kernel_launch(void* const* d_in, const int* in_sizes, int n_in,
                              void* d_out, int out_size, void* d_ws, size_t ws_size,
                              hipStream_t stream){
  const float* x     = (const float*)d_in[0];
  const float* hx    = (const float*)d_in[1];
  const float* cx    = (const float*)d_in[2];
  const int*   esrc  = (const int*)d_in[3];
  const int*   edst  = (const int*)d_in[4];
  const float* ew    = (const float*)d_in[5];
  const float* gcn_w = (const float*)d_in[6];
  const float* bias  = (const float*)d_in[7];
  const float* x2hw  = (const float*)d_in[8];
  const float* x2hb  = (const float*)d_in[9];
  const float* h2hw  = (const float*)d_in[10];
  const float* h2hb  = (const float*)d_in[11];
  const float* bn_g  = (const float*)d_in[12];
  const float* bn_b  = (const float*)d_in[13];
  const float* bn_m  = (const float*)d_in[14];
  const float* bn_v  = (const float*)d_in[15];
  float* out = (float*)d_out;

  char* w = (char*)d_ws;
  u16* support = (u16*)w; w += (((size_t)NN * HH * 2) + 255) & ~(size_t)255;
  u16* hbn     = (u16*)w; w += (((size_t)NN * HH * 2) + 255) & ~(size_t)255;
  u16* hxb     = (u16*)w; w += (((size_t)NN * HH * 2) + 255) & ~(size_t)255;
  int* counts  = (int*)w; w += (((size_t)NN * 4) + 255) & ~(size_t)255;
  int* offs    = (int*)w; w += (((size_t)NN * 4) + 255) & ~(size_t)255;
  int* cursor  = (int*)w; w += (((size_t)NN * 4) + 255) & ~(size_t)255;
  int* bsums   = (int*)w; w += (((size_t)SCAN_NB * 4) + 255) & ~(size_t)255;
  int2* esw    = (int2*)w; w += (((size_t)NE * 8) + 255) & ~(size_t)255;
  u16* wcat    = (u16*)w; w += (((size_t)512 * 256 * 2) + 255) & ~(size_t)255;
  u16* wgcn    = (u16*)w; w += (((size_t)128 * 128 * 2) + 255) & ~(size_t)255;
  float* bsum  = (float*)w; w += (((size_t)512 * 4) + 255) & ~(size_t)255;

  prep_pack<<<512, 256, 0, stream>>>(x2hw, h2hw, x2hb, h2hb, gcn_w, wcat, wgcn, bsum, counts);
  hist_kernel<<<(NE + 255) / 256, 256, 0, stream>>>(edst, counts, NE);
  scan_bsum<<<SCAN_NB, 256, 0, stream>>>(counts, bsums, NN);
  scan_tops<<<1, 256, 0, stream>>>(bsums, SCAN_NB);
  scan_final<<<SCAN_NB, 256, 0, stream>>>(counts, bsums, offs, cursor, NN);
  scatter_kernel<<<(NE + 255) / 256, 256, 0, stream>>>(esrc, edst, ew, cursor, esw, NE);
  support_mfma<<<(NN + 63) / 64, 256, 0, stream>>>(x, wgcn, support, NN);
  agg_bn3<<<(NN + 3) / 4, 256, 0, stream>>>(support, esw, offs, counts,
                                            bias, bn_g, bn_b, bn_m, bn_v, hx, hbn, hxb, NN);
  gates_mfma6<<<512, 1024, 0, stream>>>(hbn, hxb, wcat, bsum, cx, out, NN);
}

// Round 9
// 349.548 us; speedup vs baseline: 1.0317x; 1.0317x over previous
//
#include <hip/hip_runtime.h>

#define NN 50000
#define NE 800000
#define HH 128
#define BN_EPS 1e-5f
#define SCAN_NB ((NN + 255) / 256)   // 196 blocks of 256
#define PREP_NB 512                  // prep_pack blocks in fused launch
#define HIST_NB ((NE + 255) / 256)   // 3125
#define SCAT_NB ((NE + 255) / 256)   // 3125
#define SUPP_NB ((NN + 63) / 64)     // 782

typedef unsigned short u16;
typedef unsigned int u32;
typedef short bf16x8 __attribute__((ext_vector_type(8)));
typedef float f32x4 __attribute__((ext_vector_type(4)));

static __device__ __forceinline__ float bf2f(u16 u){
  union { u32 i; float f; } v; v.i = ((u32)u) << 16; return v.f;
}
static __device__ __forceinline__ u16 f2bf(float f){
  union { float f; u32 i; } v; v.f = f;
  u32 x = v.i;
  return (u16)((x + 0x7fffu + ((x >> 16) & 1u)) >> 16);
}
static __device__ __forceinline__ float sigm(float x){
  return 1.f / (1.f + __expf(-x));
}
static __device__ __forceinline__ float tanh_fast(float x){
  return 1.f - 2.f / (1.f + __expf(2.f * x));
}

// ---------------- fused: prep_pack (blocks [0,512)) + hist (blocks [512,512+3125)) ----------------
// counts[] must be zeroed BEFORE this launch (hipMemsetAsync) since hist
// atomics run concurrently with prep blocks.
// wcat stored FRAGMENT-SEQUENTIAL: [ntile(32)][kk(8)][lane(64)][e(8)],
// n = ntile*16 + (lane&15), k = kk*32 + (lane>>4)*8 + e.
__global__ __launch_bounds__(256) void fused_prep_hist(
    const float* __restrict__ x2hw, const float* __restrict__ h2hw,
    const float* __restrict__ x2hb, const float* __restrict__ h2hb,
    const float* __restrict__ gcnw,
    u16* __restrict__ wcat, u16* __restrict__ wgcn, float* __restrict__ bsum,
    const int* __restrict__ edst, int* __restrict__ counts){
  int bid = blockIdx.x;
  if (bid < PREP_NB){
    int i = bid * 256 + threadIdx.x;               // [0,131072)
    int n = i >> 8, k = i & 255;
    float v = (k < 128) ? x2hw[n * 128 + k] : h2hw[n * 128 + (k - 128)];
    int nt = n >> 4, lc = n & 15;
    int kk = k >> 5, lq = (k >> 3) & 3, e = k & 7;
    wcat[(((nt * 8 + kk) * 64) + lq * 16 + lc) * 8 + e] = f2bf(v);
    if (i < 16384){
      int nn = i >> 7, kx = i & 127;
      wgcn[i] = f2bf(gcnw[kx * 128 + nn]);         // transpose [k][n] -> [n][k]
    }
    if (i < 512) bsum[i] = x2hb[i] + h2hb[i];
  } else {
    int e = (bid - PREP_NB) * 256 + threadIdx.x;
    if (e < NE) atomicAdd(&counts[edst[e]], 1);
  }
}

// ---- parallel scan, 2 launches: per-block sums, then fold tops-scan into final ----

__global__ __launch_bounds__(256) void scan_bsum(
    const int* __restrict__ counts, int* __restrict__ bsums, int n){
  int i = blockIdx.x * 256 + threadIdx.x;
  int v = (i < n) ? counts[i] : 0;
#pragma unroll
  for (int off = 1; off < 64; off <<= 1) v += __shfl_xor(v, off);
  __shared__ int ws[4];
  if ((threadIdx.x & 63) == 0) ws[threadIdx.x >> 6] = v;
  __syncthreads();
  if (threadIdx.x == 0) bsums[blockIdx.x] = ws[0] + ws[1] + ws[2] + ws[3];
}

// each block re-scans the 196 block sums itself (cheap), then scans its slice
__global__ __launch_bounds__(256) void scan_final2(
    const int* __restrict__ counts, const int* __restrict__ bsums,
    int* __restrict__ offs, int* __restrict__ cursor, int n, int nb){
  __shared__ int sh[256], bs[256];
  int t = threadIdx.x;
  // inclusive scan of block sums
  int bv = (t < nb) ? bsums[t] : 0;
  bs[t] = bv;
  __syncthreads();
  for (int off = 1; off < 256; off <<= 1){
    int u = (t >= off) ? bs[t - off] : 0;
    __syncthreads();
    bs[t] += u;
    __syncthreads();
  }
  int bexcl = (blockIdx.x > 0) ? bs[blockIdx.x - 1] : 0;
  // local slice scan
  int i = blockIdx.x * 256 + t;
  int v = (i < n) ? counts[i] : 0;
  sh[t] = v;
  __syncthreads();
  for (int off = 1; off < 256; off <<= 1){
    int u = (t >= off) ? sh[t - off] : 0;
    __syncthreads();
    sh[t] += u;
    __syncthreads();
  }
  int excl = sh[t] - v + bexcl;
  if (i < n){ offs[i] = excl; cursor[i] = excl; }
}

// ---------------- fused: scatter (blocks [0,3125)) + support GEMM (blocks [3125,3907)) ----------------
// independent work overlapped in one launch: atomic/BW-bound scatter alongside
// the VALU/MFMA-bound support = x @ gcn_weight.
__global__ __launch_bounds__(256) void fused_scatter_support(
    const int* __restrict__ src, const int* __restrict__ dst,
    const float* __restrict__ w, int* __restrict__ cursor, int2* __restrict__ esw,
    const float* __restrict__ x, const u16* __restrict__ wgcn,
    u16* __restrict__ support, int N){
  int bid = blockIdx.x;
  if (bid < SCAT_NB){
    int e = bid * 256 + threadIdx.x;
    if (e < NE){
      int d = dst[e];
      int pos = atomicAdd(&cursor[d], 1);
      esw[pos] = make_int2(src[e], __float_as_int(w[e]));
    }
    return;
  }
  int sbid = bid - SCAT_NB;
  int tid = threadIdx.x;
  int wave = tid >> 6, lane = tid & 63;
  int c = lane & 15, q = lane >> 4;
  int row0 = sbid * 64 + wave * 16;
  int arow = row0 + c; if (arow > N - 1) arow = N - 1;   // clamp OOB reads
  f32x4 acc[8];
#pragma unroll
  for (int t = 0; t < 8; t++) acc[t] = (f32x4){0.f, 0.f, 0.f, 0.f};

  const u16* wp = wgcn + (size_t)c * 128 + q * 8;
#pragma unroll
  for (int k0 = 0; k0 < 128; k0 += 32){
    const float* ap = x + (size_t)arow * 128 + k0 + q * 8;
    float4 f0 = *(const float4*)ap;
    float4 f1 = *(const float4*)(ap + 4);
    u16 tmp[8] = {f2bf(f0.x), f2bf(f0.y), f2bf(f0.z), f2bf(f0.w),
                  f2bf(f1.x), f2bf(f1.y), f2bf(f1.z), f2bf(f1.w)};
    bf16x8 afrag = *(bf16x8*)tmp;
#pragma unroll
    for (int t = 0; t < 8; t++){
      bf16x8 bfrag = *(const bf16x8*)(wp + (size_t)t * 16 * 128 + k0);
      acc[t] = __builtin_amdgcn_mfma_f32_16x16x32_bf16(afrag, bfrag, acc[t], 0, 0, 0);
    }
  }
#pragma unroll
  for (int t = 0; t < 8; t++){
#pragma unroll
    for (int j = 0; j < 4; j++){
      int r = row0 + q * 4 + j;
      if (r < N) support[(size_t)r * 128 + t * 16 + c] = f2bf(acc[t][j]);
    }
  }
}

// ---------------- CSR aggregate + relu + bias + BN -> h_bn (bf16) ----------------
// Wave-uniform edge metadata loads (s_load), 8 independent gathers in flight;
// fmaf chain order identical to serial loop (bit-exact).
__global__ __launch_bounds__(256) void agg_bn3(
    const u16* __restrict__ support, const int2* __restrict__ esw,
    const int* __restrict__ offs, const int* __restrict__ counts,
    const float* __restrict__ bias, const float* __restrict__ gamma,
    const float* __restrict__ beta, const float* __restrict__ mean,
    const float* __restrict__ var, const float* __restrict__ hx,
    u16* __restrict__ hbn, u16* __restrict__ hxb, int N){
  int wid = blockIdx.x * 4 + (threadIdx.x >> 6);
  int lane = threadIdx.x & 63;
  if (wid >= N) return;
  int c = lane * 2;
  float2 hv = *(const float2*)(hx + (size_t)wid * HH + c);
  int start = offs[wid];
  int deg   = counts[wid];
  float a0 = 0.f, a1 = 0.f;
  int e = 0;
  for (; e + 8 <= deg; e += 8){
    int2 ev[8]; u32 u[8];
#pragma unroll
    for (int k = 0; k < 8; k++) ev[k] = esw[start + e + k];   // uniform -> s_load
#pragma unroll
    for (int k = 0; k < 8; k++)
      u[k] = *(const u32*)(support + (size_t)ev[k].x * HH + c);
#pragma unroll
    for (int k = 0; k < 8; k++){
      float g = __int_as_float(ev[k].y);
      a0 = fmaf(g, bf2f((u16)(u[k] & 0xffffu)), a0);
      a1 = fmaf(g, bf2f((u16)(u[k] >> 16)), a1);
    }
  }
  for (; e + 4 <= deg; e += 4){
    int2 ev[4]; u32 u[4];
#pragma unroll
    for (int k = 0; k < 4; k++) ev[k] = esw[start + e + k];
#pragma unroll
    for (int k = 0; k < 4; k++)
      u[k] = *(const u32*)(support + (size_t)ev[k].x * HH + c);
#pragma unroll
    for (int k = 0; k < 4; k++){
      float g = __int_as_float(ev[k].y);
      a0 = fmaf(g, bf2f((u16)(u[k] & 0xffffu)), a0);
      a1 = fmaf(g, bf2f((u16)(u[k] >> 16)), a1);
    }
  }
  for (; e < deg; e++){
    int2 ev = esw[start + e];
    float g = __int_as_float(ev.y);
    u32 ui = *(const u32*)(support + (size_t)ev.x * HH + c);
    a0 = fmaf(g, bf2f((u16)(ui & 0xffffu)), a0);
    a1 = fmaf(g, bf2f((u16)(ui >> 16)), a1);
  }
  float h0 = fmaxf(a0, 0.f) + bias[c];
  float h1 = fmaxf(a1, 0.f) + bias[c + 1];
  float s0 = gamma[c]     * rsqrtf(var[c]     + BN_EPS);
  float s1 = gamma[c + 1] * rsqrtf(var[c + 1] + BN_EPS);
  float r0 = (h0 - mean[c])     * s0 + beta[c];
  float r1 = (h1 - mean[c + 1]) * s1 + beta[c + 1];
  u32 pack = (u32)f2bf(r0) | ((u32)f2bf(r1) << 16);
  *(u32*)(hbn + (size_t)wid * HH + c) = pack;
  u32 hp = (u32)f2bf(hv.x) | ((u32)f2bf(hv.y) << 16);
  *(u32*)(hxb + (size_t)wid * HH + c) = hp;
}

// ---------------- gates GEMM v7: 512-thread blocks, 2 blocks/CU ----------------
// Round-8 lesson: 1024-thread blocks at ~96 unified regs/wave can NEVER fit
// 2/CU (needs 8 waves/SIMD x 96 = 768 > 512 regs) -> barrier drain exposed.
// v7: block = 16 rows x 64 h-cols (h-half via blockIdx.y) x all 4 gates,
// 8 waves = 4 col-groups x 2 k-halves. lbuf 32 KB. __launch_bounds__(512,4)
// caps regs at 128 -> 4 waves/SIMD = TWO blocks/CU with independent barriers:
// one block's vmcnt(0) barrier-drain hides under the other's MFMA/epilogue.
// A read 2x but hbn/hxb are L3-warm (round-7: FETCH 32.7MB < ideal reads).
__global__ __launch_bounds__(512, 4) void gates_mfma7(
    const u16* __restrict__ hbn, const u16* __restrict__ hxb,
    const u16* __restrict__ wcat, const float* __restrict__ bsum,
    const float* __restrict__ cx, float* __restrict__ out, int N){
  __shared__ float lbuf[2][4][16][64];           // 32 KB, [buf][cw][g*4+j][lane]
  int tid = threadIdx.x;
  int wave = tid >> 6, lane = tid & 63;
  int c = lane & 15, q = lane >> 4;
  int cw = wave & 3, kh = wave >> 2;             // 4 col-groups, 2 k-halves
  int hh = blockIdx.y;                           // h-half [0,2)
  int hloc = hh * 64 + cw * 16 + c;              // h in [0,128)

  // resident B: 4 gates x this wave's k-half (4 kk steps) = 64 VGPR
  const bf16x8* wsrc = (const bf16x8*)wcat;
  bf16x8 btile[4][4];
#pragma unroll
  for (int g = 0; g < 4; g++)
#pragma unroll
    for (int kk = 0; kk < 4; kk++)
      btile[g][kk] = wsrc[((size_t)((g * 8 + hh * 4 + cw) * 8) + kh * 4 + kk) * 64 + lane];

  float bi = 0.f, bf_ = 0.f, bg = 0.f, bo = 0.f;
  if (kh == 0){
    bi  = bsum[hloc];
    bf_ = bsum[128 + hloc];
    bg  = bsum[256 + hloc];
    bo  = bsum[384 + hloc];
  }
  const u16* abuf = kh ? hxb : hbn;              // each wave reads ONE A matrix
  const size_t NH = (size_t)N * HH;
  const int nchunk = N >> 4;                     // 3125 (N = 50000 = 3125*16)
  int p = 0;
  int chunk = blockIdx.x;

  // preload first chunk's A fragments
  bf16x8 a_cur[4];
  if (chunk < nchunk){
    const u16* ap = abuf + (size_t)((chunk << 4) + c) * 128 + q * 8;
#pragma unroll
    for (int kk = 0; kk < 4; kk++) a_cur[kk] = *(const bf16x8*)(ap + kk * 32);
  }

  for (; chunk < nchunk; chunk += gridDim.x){
    int row0 = chunk << 4;
    // issue next chunk's A loads NOW (in flight across MFMA+barrier+epilogue)
    int nxt = chunk + gridDim.x;
    int prow = (nxt < nchunk) ? (nxt << 4) : 0;  // clamp: loads valid, unused
    const u16* pnp = abuf + (size_t)(prow + c) * 128 + q * 8;
    bf16x8 a_nxt[4];
#pragma unroll
    for (int kk = 0; kk < 4; kk++) a_nxt[kk] = *(const bf16x8*)(pnp + kk * 32);
    // issue this chunk's cx loads early (kh=0 only; used after the barrier)
    float cxv[4];
    if (kh == 0){
#pragma unroll
      for (int j = 0; j < 4; j++)
        cxv[j] = cx[(size_t)(row0 + q * 4 + j) * HH + hloc];
    }

    f32x4 acc[4];
#pragma unroll
    for (int g = 0; g < 4; g++) acc[g] = (f32x4){0.f, 0.f, 0.f, 0.f};
#pragma unroll
    for (int kk = 0; kk < 4; kk++){
#pragma unroll
      for (int g = 0; g < 4; g++)
        acc[g] = __builtin_amdgcn_mfma_f32_16x16x32_bf16(a_cur[kk], btile[g][kk], acc[g], 0, 0, 0);
    }
    if (kh == 1){
#pragma unroll
      for (int g = 0; g < 4; g++)
#pragma unroll
        for (int j = 0; j < 4; j++)
          lbuf[p][cw][g * 4 + j][lane] = acc[g][j];
    }
    __syncthreads();
    if (kh == 0){
#pragma unroll
      for (int j = 0; j < 4; j++){
        int r = row0 + q * 4 + j;
        float gi = acc[0][j] + lbuf[p][cw][0 + j][lane]  + bi;
        float gf = acc[1][j] + lbuf[p][cw][4 + j][lane]  + bf_;
        float gg = acc[2][j] + lbuf[p][cw][8 + j][lane]  + bg;
        float go = acc[3][j] + lbuf[p][cw][12 + j][lane] + bo;
        float is = sigm(gi), fs = sigm(gf), gt = tanh_fast(gg), os = sigm(go);
        float cyv = cxv[j] * fs + is * gt;
        out[(size_t)r * HH + hloc]      = os * tanh_fast(cyv);
        out[NH + (size_t)r * HH + hloc] = cyv;
      }
    }
#pragma unroll
    for (int kk = 0; kk < 4; kk++) a_cur[kk] = a_nxt[kk];
    p ^= 1;
  }
}

// ---------------- launch ----------------

extern "C" void kernel_launch(void* const* d_in, const int* in_sizes, int n_in,
                              void* d_out, int out_size, void* d_ws, size_t ws_size,
                              hipStream_t stream){
  const float* x     = (const float*)d_in[0];
  const float* hx    = (const float*)d_in[1];
  const float* cx    = (const float*)d_in[2];
  const int*   esrc  = (const int*)d_in[3];
  const int*   edst  = (const int*)d_in[4];
  const float* ew    = (const float*)d_in[5];
  const float* gcn_w = (const float*)d_in[6];
  const float* bias  = (const float*)d_in[7];
  const float* x2hw  = (const float*)d_in[8];
  const float* x2hb  = (const float*)d_in[9];
  const float* h2hw  = (const float*)d_in[10];
  const float* h2hb  = (const float*)d_in[11];
  const float* bn_g  = (const float*)d_in[12];
  const float* bn_b  = (const float*)d_in[13];
  const float* bn_m  = (const float*)d_in[14];
  const float* bn_v  = (const float*)d_in[15];
  float* out = (float*)d_out;

  char* w = (char*)d_ws;
  u16* support = (u16*)w; w += (((size_t)NN * HH * 2) + 255) & ~(size_t)255;
  u16* hbn     = (u16*)w; w += (((size_t)NN * HH * 2) + 255) & ~(size_t)255;
  u16* hxb     = (u16*)w; w += (((size_t)NN * HH * 2) + 255) & ~(size_t)255;
  int* counts  = (int*)w; w += (((size_t)NN * 4) + 255) & ~(size_t)255;
  int* offs    = (int*)w; w += (((size_t)NN * 4) + 255) & ~(size_t)255;
  int* cursor  = (int*)w; w += (((size_t)NN * 4) + 255) & ~(size_t)255;
  int* bsums   = (int*)w; w += (((size_t)SCAN_NB * 4) + 255) & ~(size_t)255;
  int2* esw    = (int2*)w; w += (((size_t)NE * 8) + 255) & ~(size_t)255;
  u16* wcat    = (u16*)w; w += (((size_t)512 * 256 * 2) + 255) & ~(size_t)255;
  u16* wgcn    = (u16*)w; w += (((size_t)128 * 128 * 2) + 255) & ~(size_t)255;
  float* bsum  = (float*)w; w += (((size_t)512 * 4) + 255) & ~(size_t)255;

  hipMemsetAsync(counts, 0, (size_t)NN * 4, stream);
  fused_prep_hist<<<PREP_NB + HIST_NB, 256, 0, stream>>>(
      x2hw, h2hw, x2hb, h2hb, gcn_w, wcat, wgcn, bsum, edst, counts);
  scan_bsum<<<SCAN_NB, 256, 0, stream>>>(counts, bsums, NN);
  scan_final2<<<SCAN_NB, 256, 0, stream>>>(counts, bsums, offs, cursor, NN, SCAN_NB);
  fused_scatter_support<<<SCAT_NB + SUPP_NB, 256, 0, stream>>>(
      esrc, edst, ew, cursor, esw, x, wgcn, support, NN);
  agg_bn3<<<(NN + 3) / 4, 256, 0, stream>>>(support, esw, offs, counts,
                                            bias, bn_g, bn_b, bn_m, bn_v, hx, hbn, hxb, NN);
  gates_mfma7<<<dim3(256, 2), 512, 0, stream>>>(hbn, hxb, wcat, bsum, cx, out, NN);
}

// Round 11
// 337.526 us; speedup vs baseline: 1.0685x; 1.0356x over previous
//
#include <hip/hip_runtime.h>

#define NN 50000
#define NE 800000
#define HH 128
#define BN_EPS 1e-5f
#define SCAN_NB ((NN + 255) / 256)        // 196 blocks of 256
#define PREP_NB 512                       // prep_pack blocks in fused launch
#define EPB 2048                          // edges per block at 8 edges/thread
#define HIST_NB ((NE + EPB - 1) / EPB)    // 391
#define SCAT_NB ((NE + EPB - 1) / EPB)    // 391
#define SUPP_NB ((NN + 63) / 64)          // 782

typedef unsigned short u16;
typedef unsigned int u32;
typedef short bf16x8 __attribute__((ext_vector_type(8)));
typedef float f32x4 __attribute__((ext_vector_type(4)));

static __device__ __forceinline__ float bf2f(u16 u){
  union { u32 i; float f; } v; v.i = ((u32)u) << 16; return v.f;
}
static __device__ __forceinline__ u16 f2bf(float f){
  union { float f; u32 i; } v; v.f = f;
  u32 x = v.i;
  return (u16)((x + 0x7fffu + ((x >> 16) & 1u)) >> 16);
}
static __device__ __forceinline__ float sigm(float x){
  return 1.f / (1.f + __expf(-x));
}
static __device__ __forceinline__ float tanh_fast(float x){
  return 1.f - 2.f / (1.f + __expf(2.f * x));
}

// ---------------- fused: prep_pack (blocks [0,512)) + hist (blocks [512,512+391)) ----------------
// counts[] zeroed by hipMemsetAsync before this launch.
// hist: 8 edges/thread, int4-vectorized edst reads; atomics are fire-and-forget
// (no return value -> no dependent chain).
// wcat stored FRAGMENT-SEQUENTIAL: [ntile(32)][kk(8)][lane(64)][e(8)],
// n = ntile*16 + (lane&15), k = kk*32 + (lane>>4)*8 + e.
__global__ __launch_bounds__(256) void fused_prep_hist(
    const float* __restrict__ x2hw, const float* __restrict__ h2hw,
    const float* __restrict__ x2hb, const float* __restrict__ h2hb,
    const float* __restrict__ gcnw,
    u16* __restrict__ wcat, u16* __restrict__ wgcn, float* __restrict__ bsum,
    const int* __restrict__ edst, int* __restrict__ counts){
  int bid = blockIdx.x;
  if (bid < PREP_NB){
    int i = bid * 256 + threadIdx.x;               // [0,131072)
    int n = i >> 8, k = i & 255;
    float v = (k < 128) ? x2hw[n * 128 + k] : h2hw[n * 128 + (k - 128)];
    int nt = n >> 4, lc = n & 15;
    int kk = k >> 5, lq = (k >> 3) & 3, e = k & 7;
    wcat[(((nt * 8 + kk) * 64) + lq * 16 + lc) * 8 + e] = f2bf(v);
    if (i < 16384){
      int nn = i >> 7, kx = i & 127;
      wgcn[i] = f2bf(gcnw[kx * 128 + nn]);         // transpose [k][n] -> [n][k]
    }
    if (i < 512) bsum[i] = x2hb[i] + h2hb[i];
  } else {
    int base = (bid - PREP_NB) * EPB + threadIdx.x * 8;
    if (base + 8 <= NE){
      int4 d0 = *(const int4*)(edst + base);
      int4 d1 = *(const int4*)(edst + base + 4);
      atomicAdd(&counts[d0.x], 1); atomicAdd(&counts[d0.y], 1);
      atomicAdd(&counts[d0.z], 1); atomicAdd(&counts[d0.w], 1);
      atomicAdd(&counts[d1.x], 1); atomicAdd(&counts[d1.y], 1);
      atomicAdd(&counts[d1.z], 1); atomicAdd(&counts[d1.w], 1);
    } else {
      for (int e = base; e < NE; e++) atomicAdd(&counts[edst[e]], 1);
    }
  }
}

// ---- parallel scan, 2 launches: per-block sums, then fold tops-scan into final ----

__global__ __launch_bounds__(256) void scan_bsum(
    const int* __restrict__ counts, int* __restrict__ bsums, int n){
  int i = blockIdx.x * 256 + threadIdx.x;
  int v = (i < n) ? counts[i] : 0;
#pragma unroll
  for (int off = 1; off < 64; off <<= 1) v += __shfl_xor(v, off);
  __shared__ int ws[4];
  if ((threadIdx.x & 63) == 0) ws[threadIdx.x >> 6] = v;
  __syncthreads();
  if (threadIdx.x == 0) bsums[blockIdx.x] = ws[0] + ws[1] + ws[2] + ws[3];
}

// each block re-scans the 196 block sums itself (cheap), then scans its slice
__global__ __launch_bounds__(256) void scan_final2(
    const int* __restrict__ counts, const int* __restrict__ bsums,
    int* __restrict__ offs, int* __restrict__ cursor, int n, int nb){
  __shared__ int sh[256], bs[256];
  int t = threadIdx.x;
  int bv = (t < nb) ? bsums[t] : 0;
  bs[t] = bv;
  __syncthreads();
  for (int off = 1; off < 256; off <<= 1){
    int u = (t >= off) ? bs[t - off] : 0;
    __syncthreads();
    bs[t] += u;
    __syncthreads();
  }
  int bexcl = (blockIdx.x > 0) ? bs[blockIdx.x - 1] : 0;
  int i = blockIdx.x * 256 + t;
  int v = (i < n) ? counts[i] : 0;
  sh[t] = v;
  __syncthreads();
  for (int off = 1; off < 256; off <<= 1){
    int u = (t >= off) ? sh[t - off] : 0;
    __syncthreads();
    sh[t] += u;
    __syncthreads();
  }
  int excl = sh[t] - v + bexcl;
  if (i < n){ offs[i] = excl; cursor[i] = excl; }
}

// ---------------- fused: support GEMM (blocks [0,782)) + scatter (blocks [782,782+391)) ----------------
// support blocks FIRST so the MFMA-heavy work starts at t=0 and the
// latency-bound scatter fills in around it.
// scatter: 8 edges/thread -> 8 independent {atomicAdd-with-return -> store}
// chains in flight per thread (round-9: 1 chain/thread = 85us, all pipes idle).
__global__ __launch_bounds__(256) void fused_support_scatter(
    const float* __restrict__ x, const u16* __restrict__ wgcn,
    u16* __restrict__ support,
    const int* __restrict__ src, const int* __restrict__ dst,
    const float* __restrict__ w, int* __restrict__ cursor, int2* __restrict__ esw,
    int N){
  int bid = blockIdx.x;
  if (bid >= SUPP_NB){
    int base = (bid - SUPP_NB) * EPB + threadIdx.x * 8;
    if (base + 8 <= NE){
      int4 d0 = *(const int4*)(dst + base);
      int4 d1 = *(const int4*)(dst + base + 4);
      int4 s0 = *(const int4*)(src + base);
      int4 s1 = *(const int4*)(src + base + 4);
      float4 w0 = *(const float4*)(w + base);
      float4 w1 = *(const float4*)(w + base + 4);
      int   d[8] = {d0.x, d0.y, d0.z, d0.w, d1.x, d1.y, d1.z, d1.w};
      int   s[8] = {s0.x, s0.y, s0.z, s0.w, s1.x, s1.y, s1.z, s1.w};
      float g[8] = {w0.x, w0.y, w0.z, w0.w, w1.x, w1.y, w1.z, w1.w};
      int pos[8];
#pragma unroll
      for (int k = 0; k < 8; k++) pos[k] = atomicAdd(&cursor[d[k]], 1);
#pragma unroll
      for (int k = 0; k < 8; k++) esw[pos[k]] = make_int2(s[k], __float_as_int(g[k]));
    } else {
      for (int e = base; e < NE; e++){
        int pos = atomicAdd(&cursor[dst[e]], 1);
        esw[pos] = make_int2(src[e], __float_as_int(w[e]));
      }
    }
    return;
  }
  int tid = threadIdx.x;
  int wave = tid >> 6, lane = tid & 63;
  int c = lane & 15, q = lane >> 4;
  int row0 = bid * 64 + wave * 16;
  int arow = row0 + c; if (arow > N - 1) arow = N - 1;   // clamp OOB reads
  f32x4 acc[8];
#pragma unroll
  for (int t = 0; t < 8; t++) acc[t] = (f32x4){0.f, 0.f, 0.f, 0.f};

  const u16* wp = wgcn + (size_t)c * 128 + q * 8;
#pragma unroll
  for (int k0 = 0; k0 < 128; k0 += 32){
    const float* ap = x + (size_t)arow * 128 + k0 + q * 8;
    float4 f0 = *(const float4*)ap;
    float4 f1 = *(const float4*)(ap + 4);
    u16 tmp[8] = {f2bf(f0.x), f2bf(f0.y), f2bf(f0.z), f2bf(f0.w),
                  f2bf(f1.x), f2bf(f1.y), f2bf(f1.z), f2bf(f1.w)};
    bf16x8 afrag = *(bf16x8*)tmp;
#pragma unroll
    for (int t = 0; t < 8; t++){
      bf16x8 bfrag = *(const bf16x8*)(wp + (size_t)t * 16 * 128 + k0);
      acc[t] = __builtin_amdgcn_mfma_f32_16x16x32_bf16(afrag, bfrag, acc[t], 0, 0, 0);
    }
  }
#pragma unroll
  for (int t = 0; t < 8; t++){
#pragma unroll
    for (int j = 0; j < 4; j++){
      int r = row0 + q * 4 + j;
      if (r < N) support[(size_t)r * 128 + t * 16 + c] = f2bf(acc[t][j]);
    }
  }
}

// ---------------- CSR aggregate + relu + bias + BN -> h_bn (bf16) ----------------
// Wave-uniform edge metadata loads (s_load), 8 independent gathers in flight;
// fmaf chain order identical to serial loop (bit-exact).
__global__ __launch_bounds__(256) void agg_bn3(
    const u16* __restrict__ support, const int2* __restrict__ esw,
    const int* __restrict__ offs, const int* __restrict__ counts,
    const float* __restrict__ bias, const float* __restrict__ gamma,
    const float* __restrict__ beta, const float* __restrict__ mean,
    const float* __restrict__ var, const float* __restrict__ hx,
    u16* __restrict__ hbn, u16* __restrict__ hxb, int N){
  int wid = blockIdx.x * 4 + (threadIdx.x >> 6);
  int lane = threadIdx.x & 63;
  if (wid >= N) return;
  int c = lane * 2;
  float2 hv = *(const float2*)(hx + (size_t)wid * HH + c);
  int start = offs[wid];
  int deg   = counts[wid];
  float a0 = 0.f, a1 = 0.f;
  int e = 0;
  for (; e + 8 <= deg; e += 8){
    int2 ev[8]; u32 u[8];
#pragma unroll
    for (int k = 0; k < 8; k++) ev[k] = esw[start + e + k];   // uniform -> s_load
#pragma unroll
    for (int k = 0; k < 8; k++)
      u[k] = *(const u32*)(support + (size_t)ev[k].x * HH + c);
#pragma unroll
    for (int k = 0; k < 8; k++){
      float g = __int_as_float(ev[k].y);
      a0 = fmaf(g, bf2f((u16)(u[k] & 0xffffu)), a0);
      a1 = fmaf(g, bf2f((u16)(u[k] >> 16)), a1);
    }
  }
  for (; e + 4 <= deg; e += 4){
    int2 ev[4]; u32 u[4];
#pragma unroll
    for (int k = 0; k < 4; k++) ev[k] = esw[start + e + k];
#pragma unroll
    for (int k = 0; k < 4; k++)
      u[k] = *(const u32*)(support + (size_t)ev[k].x * HH + c);
#pragma unroll
    for (int k = 0; k < 4; k++){
      float g = __int_as_float(ev[k].y);
      a0 = fmaf(g, bf2f((u16)(u[k] & 0xffffu)), a0);
      a1 = fmaf(g, bf2f((u16)(u[k] >> 16)), a1);
    }
  }
  for (; e < deg; e++){
    int2 ev = esw[start + e];
    float g = __int_as_float(ev.y);
    u32 ui = *(const u32*)(support + (size_t)ev.x * HH + c);
    a0 = fmaf(g, bf2f((u16)(ui & 0xffffu)), a0);
    a1 = fmaf(g, bf2f((u16)(ui >> 16)), a1);
  }
  float h0 = fmaxf(a0, 0.f) + bias[c];
  float h1 = fmaxf(a1, 0.f) + bias[c + 1];
  float s0 = gamma[c]     * rsqrtf(var[c]     + BN_EPS);
  float s1 = gamma[c + 1] * rsqrtf(var[c + 1] + BN_EPS);
  float r0 = (h0 - mean[c])     * s0 + beta[c];
  float r1 = (h1 - mean[c + 1]) * s1 + beta[c + 1];
  u32 pack = (u32)f2bf(r0) | ((u32)f2bf(r1) << 16);
  *(u32*)(hbn + (size_t)wid * HH + c) = pack;
  u32 hp = (u32)f2bf(hv.x) | ((u32)f2bf(hv.y) << 16);
  *(u32*)(hxb + (size_t)wid * HH + c) = hp;
}

// ---------------- gates GEMM v7: 512-thread blocks, 2 blocks/CU ----------------
// block = 16 rows x 64 h-cols (h-half via blockIdx.y) x all 4 gates,
// 8 waves = 4 col-groups x 2 k-halves. lbuf 32 KB. __launch_bounds__(512,4)
// caps regs at 128 -> 4 waves/SIMD = TWO blocks/CU with independent barriers.
__global__ __launch_bounds__(512, 4) void gates_mfma7(
    const u16* __restrict__ hbn, const u16* __restrict__ hxb,
    const u16* __restrict__ wcat, const float* __restrict__ bsum,
    const float* __restrict__ cx, float* __restrict__ out, int N){
  __shared__ float lbuf[2][4][16][64];           // 32 KB, [buf][cw][g*4+j][lane]
  int tid = threadIdx.x;
  int wave = tid >> 6, lane = tid & 63;
  int c = lane & 15, q = lane >> 4;
  int cw = wave & 3, kh = wave >> 2;             // 4 col-groups, 2 k-halves
  int hh = blockIdx.y;                           // h-half [0,2)
  int hloc = hh * 64 + cw * 16 + c;              // h in [0,128)

  const bf16x8* wsrc = (const bf16x8*)wcat;
  bf16x8 btile[4][4];
#pragma unroll
  for (int g = 0; g < 4; g++)
#pragma unroll
    for (int kk = 0; kk < 4; kk++)
      btile[g][kk] = wsrc[((size_t)((g * 8 + hh * 4 + cw) * 8) + kh * 4 + kk) * 64 + lane];

  float bi = 0.f, bf_ = 0.f, bg = 0.f, bo = 0.f;
  if (kh == 0){
    bi  = bsum[hloc];
    bf_ = bsum[128 + hloc];
    bg  = bsum[256 + hloc];
    bo  = bsum[384 + hloc];
  }
  const u16* abuf = kh ? hxb : hbn;              // each wave reads ONE A matrix
  const size_t NH = (size_t)N * HH;
  const int nchunk = N >> 4;                     // 3125 (N = 50000 = 3125*16)
  int p = 0;
  int chunk = blockIdx.x;

  bf16x8 a_cur[4];
  if (chunk < nchunk){
    const u16* ap = abuf + (size_t)((chunk << 4) + c) * 128 + q * 8;
#pragma unroll
    for (int kk = 0; kk < 4; kk++) a_cur[kk] = *(const bf16x8*)(ap + kk * 32);
  }

  for (; chunk < nchunk; chunk += gridDim.x){
    int row0 = chunk << 4;
    int nxt = chunk + gridDim.x;
    int prow = (nxt < nchunk) ? (nxt << 4) : 0;  // clamp: loads valid, unused
    const u16* pnp = abuf + (size_t)(prow + c) * 128 + q * 8;
    bf16x8 a_nxt[4];
#pragma unroll
    for (int kk = 0; kk < 4; kk++) a_nxt[kk] = *(const bf16x8*)(pnp + kk * 32);
    float cxv[4];
    if (kh == 0){
#pragma unroll
      for (int j = 0; j < 4; j++)
        cxv[j] = cx[(size_t)(row0 + q * 4 + j) * HH + hloc];
    }

    f32x4 acc[4];
#pragma unroll
    for (int g = 0; g < 4; g++) acc[g] = (f32x4){0.f, 0.f, 0.f, 0.f};
#pragma unroll
    for (int kk = 0; kk < 4; kk++){
#pragma unroll
      for (int g = 0; g < 4; g++)
        acc[g] = __builtin_amdgcn_mfma_f32_16x16x32_bf16(a_cur[kk], btile[g][kk], acc[g], 0, 0, 0);
    }
    if (kh == 1){
#pragma unroll
      for (int g = 0; g < 4; g++)
#pragma unroll
        for (int j = 0; j < 4; j++)
          lbuf[p][cw][g * 4 + j][lane] = acc[g][j];
    }
    __syncthreads();
    if (kh == 0){
#pragma unroll
      for (int j = 0; j < 4; j++){
        int r = row0 + q * 4 + j;
        float gi = acc[0][j] + lbuf[p][cw][0 + j][lane]  + bi;
        float gf = acc[1][j] + lbuf[p][cw][4 + j][lane]  + bf_;
        float gg = acc[2][j] + lbuf[p][cw][8 + j][lane]  + bg;
        float go = acc[3][j] + lbuf[p][cw][12 + j][lane] + bo;
        float is = sigm(gi), fs = sigm(gf), gt = tanh_fast(gg), os = sigm(go);
        float cyv = cxv[j] * fs + is * gt;
        out[(size_t)r * HH + hloc]      = os * tanh_fast(cyv);
        out[NH + (size_t)r * HH + hloc] = cyv;
      }
    }
#pragma unroll
    for (int kk = 0; kk < 4; kk++) a_cur[kk] = a_nxt[kk];
    p ^= 1;
  }
}

// ---------------- launch ----------------

extern "C" void kernel_launch(void* const* d_in, const int* in_sizes, int n_in,
                              void* d_out, int out_size, void* d_ws, size_t ws_size,
                              hipStream_t stream){
  const float* x     = (const float*)d_in[0];
  const float* hx    = (const float*)d_in[1];
  const float* cx    = (const float*)d_in[2];
  const int*   esrc  = (const int*)d_in[3];
  const int*   edst  = (const int*)d_in[4];
  const float* ew    = (const float*)d_in[5];
  const float* gcn_w = (const float*)d_in[6];
  const float* bias  = (const float*)d_in[7];
  const float* x2hw  = (const float*)d_in[8];
  const float* x2hb  = (const float*)d_in[9];
  const float* h2hw  = (const float*)d_in[10];
  const float* h2hb  = (const float*)d_in[11];
  const float* bn_g  = (const float*)d_in[12];
  const float* bn_b  = (const float*)d_in[13];
  const float* bn_m  = (const float*)d_in[14];
  const float* bn_v  = (const float*)d_in[15];
  float* out = (float*)d_out;

  char* w = (char*)d_ws;
  u16* support = (u16*)w; w += (((size_t)NN * HH * 2) + 255) & ~(size_t)255;
  u16* hbn     = (u16*)w; w += (((size_t)NN * HH * 2) + 255) & ~(size_t)255;
  u16* hxb     = (u16*)w; w += (((size_t)NN * HH * 2) + 255) & ~(size_t)255;
  int* counts  = (int*)w; w += (((size_t)NN * 4) + 255) & ~(size_t)255;
  int* offs    = (int*)w; w += (((size_t)NN * 4) + 255) & ~(size_t)255;
  int* cursor  = (int*)w; w += (((size_t)NN * 4) + 255) & ~(size_t)255;
  int* bsums   = (int*)w; w += (((size_t)SCAN_NB * 4) + 255) & ~(size_t)255;
  int2* esw    = (int2*)w; w += (((size_t)NE * 8) + 255) & ~(size_t)255;
  u16* wcat    = (u16*)w; w += (((size_t)512 * 256 * 2) + 255) & ~(size_t)255;
  u16* wgcn    = (u16*)w; w += (((size_t)128 * 128 * 2) + 255) & ~(size_t)255;
  float* bsum  = (float*)w; w += (((size_t)512 * 4) + 255) & ~(size_t)255;

  hipMemsetAsync(counts, 0, (size_t)NN * 4, stream);
  fused_prep_hist<<<PREP_NB + HIST_NB, 256, 0, stream>>>(
      x2hw, h2hw, x2hb, h2hb, gcn_w, wcat, wgcn, bsum, edst, counts);
  scan_bsum<<<SCAN_NB, 256, 0, stream>>>(counts, bsums, NN);
  scan_final2<<<SCAN_NB, 256, 0, stream>>>(counts, bsums, offs, cursor, NN, SCAN_NB);
  fused_support_scatter<<<SUPP_NB + SCAT_NB, 256, 0, stream>>>(
      x, wgcn, support, esrc, edst, ew, cursor, esw, NN);
  agg_bn3<<<(NN + 3) / 4, 256, 0, stream>>>(support, esw, offs, counts,
                                            bias, bn_g, bn_b, bn_m, bn_v, hx, hbn, hxb, NN);
  gates_mfma7<<<dim3(256, 2), 512, 0, stream>>>(hbn, hxb, wcat, bsum, cx, out, NN);
}

// Round 12
// 331.175 us; speedup vs baseline: 1.0890x; 1.0192x over previous
//
#include <hip/hip_runtime.h>

#define NN 50000
#define NE 800000
#define HH 128
#define BN_EPS 1e-5f
#define SCAN_NB ((NN + 255) / 256)        // 196 blocks of 256
#define PREP_NB 512                       // prep_pack blocks in fused launch
#define EPB 2048                          // edges per block at 8 edges/thread
#define HIST_NB ((NE + EPB - 1) / EPB)    // 391
#define SCAT_NB ((NE + EPB - 1) / EPB)    // 391
#define SUPP_NB ((NN + 63) / 64)          // 782

typedef unsigned short u16;
typedef unsigned int u32;
typedef short bf16x8 __attribute__((ext_vector_type(8)));
typedef float f32x4 __attribute__((ext_vector_type(4)));

static __device__ __forceinline__ float bf2f(u16 u){
  union { u32 i; float f; } v; v.i = ((u32)u) << 16; return v.f;
}
static __device__ __forceinline__ u16 f2bf(float f){
  union { float f; u32 i; } v; v.f = f;
  u32 x = v.i;
  return (u16)((x + 0x7fffu + ((x >> 16) & 1u)) >> 16);
}
static __device__ __forceinline__ float sigm(float x){
  return 1.f / (1.f + __expf(-x));
}
static __device__ __forceinline__ float tanh_fast(float x){
  return 1.f - 2.f / (1.f + __expf(2.f * x));
}

// ---------------- fused: prep_pack (blocks [0,512)) + hist (blocks [512,512+391)) ----------------
// counts[] zeroed by hipMemsetAsync before this launch.
// hist: 8 edges/thread, int4-vectorized edst reads; atomics are fire-and-forget.
// wcat stored FRAGMENT-SEQUENTIAL: [ntile(32)][kk(8)][lane(64)][e(8)],
// n = ntile*16 + (lane&15), k = kk*32 + (lane>>4)*8 + e.
__global__ __launch_bounds__(256) void fused_prep_hist(
    const float* __restrict__ x2hw, const float* __restrict__ h2hw,
    const float* __restrict__ x2hb, const float* __restrict__ h2hb,
    const float* __restrict__ gcnw,
    u16* __restrict__ wcat, u16* __restrict__ wgcn, float* __restrict__ bsum,
    const int* __restrict__ edst, int* __restrict__ counts){
  int bid = blockIdx.x;
  if (bid < PREP_NB){
    int i = bid * 256 + threadIdx.x;               // [0,131072)
    int n = i >> 8, k = i & 255;
    float v = (k < 128) ? x2hw[n * 128 + k] : h2hw[n * 128 + (k - 128)];
    int nt = n >> 4, lc = n & 15;
    int kk = k >> 5, lq = (k >> 3) & 3, e = k & 7;
    wcat[(((nt * 8 + kk) * 64) + lq * 16 + lc) * 8 + e] = f2bf(v);
    if (i < 16384){
      int nn = i >> 7, kx = i & 127;
      wgcn[i] = f2bf(gcnw[kx * 128 + nn]);         // transpose [k][n] -> [n][k]
    }
    if (i < 512) bsum[i] = x2hb[i] + h2hb[i];
  } else {
    int base = (bid - PREP_NB) * EPB + threadIdx.x * 8;
    if (base + 8 <= NE){
      int4 d0 = *(const int4*)(edst + base);
      int4 d1 = *(const int4*)(edst + base + 4);
      atomicAdd(&counts[d0.x], 1); atomicAdd(&counts[d0.y], 1);
      atomicAdd(&counts[d0.z], 1); atomicAdd(&counts[d0.w], 1);
      atomicAdd(&counts[d1.x], 1); atomicAdd(&counts[d1.y], 1);
      atomicAdd(&counts[d1.z], 1); atomicAdd(&counts[d1.w], 1);
    } else {
      for (int e = base; e < NE; e++) atomicAdd(&counts[edst[e]], 1);
    }
  }
}

// ---- parallel scan, 2 launches: per-block sums, then fold tops-scan into final ----

__global__ __launch_bounds__(256) void scan_bsum(
    const int* __restrict__ counts, int* __restrict__ bsums, int n){
  int i = blockIdx.x * 256 + threadIdx.x;
  int v = (i < n) ? counts[i] : 0;
#pragma unroll
  for (int off = 1; off < 64; off <<= 1) v += __shfl_xor(v, off);
  __shared__ int ws[4];
  if ((threadIdx.x & 63) == 0) ws[threadIdx.x >> 6] = v;
  __syncthreads();
  if (threadIdx.x == 0) bsums[blockIdx.x] = ws[0] + ws[1] + ws[2] + ws[3];
}

// each block re-scans the 196 block sums itself (cheap), then scans its slice
__global__ __launch_bounds__(256) void scan_final2(
    const int* __restrict__ counts, const int* __restrict__ bsums,
    int* __restrict__ offs, int* __restrict__ cursor, int n, int nb){
  __shared__ int sh[256], bs[256];
  int t = threadIdx.x;
  int bv = (t < nb) ? bsums[t] : 0;
  bs[t] = bv;
  __syncthreads();
  for (int off = 1; off < 256; off <<= 1){
    int u = (t >= off) ? bs[t - off] : 0;
    __syncthreads();
    bs[t] += u;
    __syncthreads();
  }
  int bexcl = (blockIdx.x > 0) ? bs[blockIdx.x - 1] : 0;
  int i = blockIdx.x * 256 + t;
  int v = (i < n) ? counts[i] : 0;
  sh[t] = v;
  __syncthreads();
  for (int off = 1; off < 256; off <<= 1){
    int u = (t >= off) ? sh[t - off] : 0;
    __syncthreads();
    sh[t] += u;
    __syncthreads();
  }
  int excl = sh[t] - v + bexcl;
  if (i < n){ offs[i] = excl; cursor[i] = excl; }
}

// ---------------- fused: support GEMM (blocks [0,782)) + scatter (blocks [782,782+391)) ----------------
// support blocks FIRST; scatter = 8 edges/thread, 8 independent atomic chains.
__global__ __launch_bounds__(256) void fused_support_scatter(
    const float* __restrict__ x, const u16* __restrict__ wgcn,
    u16* __restrict__ support,
    const int* __restrict__ src, const int* __restrict__ dst,
    const float* __restrict__ w, int* __restrict__ cursor, int2* __restrict__ esw,
    int N){
  int bid = blockIdx.x;
  if (bid >= SUPP_NB){
    int base = (bid - SUPP_NB) * EPB + threadIdx.x * 8;
    if (base + 8 <= NE){
      int4 d0 = *(const int4*)(dst + base);
      int4 d1 = *(const int4*)(dst + base + 4);
      int4 s0 = *(const int4*)(src + base);
      int4 s1 = *(const int4*)(src + base + 4);
      float4 w0 = *(const float4*)(w + base);
      float4 w1 = *(const float4*)(w + base + 4);
      int   d[8] = {d0.x, d0.y, d0.z, d0.w, d1.x, d1.y, d1.z, d1.w};
      int   s[8] = {s0.x, s0.y, s0.z, s0.w, s1.x, s1.y, s1.z, s1.w};
      float g[8] = {w0.x, w0.y, w0.z, w0.w, w1.x, w1.y, w1.z, w1.w};
      int pos[8];
#pragma unroll
      for (int k = 0; k < 8; k++) pos[k] = atomicAdd(&cursor[d[k]], 1);
#pragma unroll
      for (int k = 0; k < 8; k++) esw[pos[k]] = make_int2(s[k], __float_as_int(g[k]));
    } else {
      for (int e = base; e < NE; e++){
        int pos = atomicAdd(&cursor[dst[e]], 1);
        esw[pos] = make_int2(src[e], __float_as_int(w[e]));
      }
    }
    return;
  }
  int tid = threadIdx.x;
  int wave = tid >> 6, lane = tid & 63;
  int c = lane & 15, q = lane >> 4;
  int row0 = bid * 64 + wave * 16;
  int arow = row0 + c; if (arow > N - 1) arow = N - 1;   // clamp OOB reads
  f32x4 acc[8];
#pragma unroll
  for (int t = 0; t < 8; t++) acc[t] = (f32x4){0.f, 0.f, 0.f, 0.f};

  const u16* wp = wgcn + (size_t)c * 128 + q * 8;
#pragma unroll
  for (int k0 = 0; k0 < 128; k0 += 32){
    const float* ap = x + (size_t)arow * 128 + k0 + q * 8;
    float4 f0 = *(const float4*)ap;
    float4 f1 = *(const float4*)(ap + 4);
    u16 tmp[8] = {f2bf(f0.x), f2bf(f0.y), f2bf(f0.z), f2bf(f0.w),
                  f2bf(f1.x), f2bf(f1.y), f2bf(f1.z), f2bf(f1.w)};
    bf16x8 afrag = *(bf16x8*)tmp;
#pragma unroll
    for (int t = 0; t < 8; t++){
      bf16x8 bfrag = *(const bf16x8*)(wp + (size_t)t * 16 * 128 + k0);
      acc[t] = __builtin_amdgcn_mfma_f32_16x16x32_bf16(afrag, bfrag, acc[t], 0, 0, 0);
    }
  }
#pragma unroll
  for (int t = 0; t < 8; t++){
#pragma unroll
    for (int j = 0; j < 4; j++){
      int r = row0 + q * 4 + j;
      if (r < N) support[(size_t)r * 128 + t * 16 + c] = f2bf(acc[t][j]);
    }
  }
}

// ---------------- CSR aggregate + relu + bias + BN -> h_bn (bf16) ----------------
// Wave-uniform edge metadata loads (s_load), 8 independent gathers in flight;
// fmaf chain order identical to serial loop (bit-exact).
__global__ __launch_bounds__(256) void agg_bn3(
    const u16* __restrict__ support, const int2* __restrict__ esw,
    const int* __restrict__ offs, const int* __restrict__ counts,
    const float* __restrict__ bias, const float* __restrict__ gamma,
    const float* __restrict__ beta, const float* __restrict__ mean,
    const float* __restrict__ var, const float* __restrict__ hx,
    u16* __restrict__ hbn, u16* __restrict__ hxb, int N){
  int wid = blockIdx.x * 4 + (threadIdx.x >> 6);
  int lane = threadIdx.x & 63;
  if (wid >= N) return;
  int c = lane * 2;
  float2 hv = *(const float2*)(hx + (size_t)wid * HH + c);
  int start = offs[wid];
  int deg   = counts[wid];
  float a0 = 0.f, a1 = 0.f;
  int e = 0;
  for (; e + 8 <= deg; e += 8){
    int2 ev[8]; u32 u[8];
#pragma unroll
    for (int k = 0; k < 8; k++) ev[k] = esw[start + e + k];   // uniform -> s_load
#pragma unroll
    for (int k = 0; k < 8; k++)
      u[k] = *(const u32*)(support + (size_t)ev[k].x * HH + c);
#pragma unroll
    for (int k = 0; k < 8; k++){
      float g = __int_as_float(ev[k].y);
      a0 = fmaf(g, bf2f((u16)(u[k] & 0xffffu)), a0);
      a1 = fmaf(g, bf2f((u16)(u[k] >> 16)), a1);
    }
  }
  for (; e + 4 <= deg; e += 4){
    int2 ev[4]; u32 u[4];
#pragma unroll
    for (int k = 0; k < 4; k++) ev[k] = esw[start + e + k];
#pragma unroll
    for (int k = 0; k < 4; k++)
      u[k] = *(const u32*)(support + (size_t)ev[k].x * HH + c);
#pragma unroll
    for (int k = 0; k < 4; k++){
      float g = __int_as_float(ev[k].y);
      a0 = fmaf(g, bf2f((u16)(u[k] & 0xffffu)), a0);
      a1 = fmaf(g, bf2f((u16)(u[k] >> 16)), a1);
    }
  }
  for (; e < deg; e++){
    int2 ev = esw[start + e];
    float g = __int_as_float(ev.y);
    u32 ui = *(const u32*)(support + (size_t)ev.x * HH + c);
    a0 = fmaf(g, bf2f((u16)(ui & 0xffffu)), a0);
    a1 = fmaf(g, bf2f((u16)(ui >> 16)), a1);
  }
  float h0 = fmaxf(a0, 0.f) + bias[c];
  float h1 = fmaxf(a1, 0.f) + bias[c + 1];
  float s0 = gamma[c]     * rsqrtf(var[c]     + BN_EPS);
  float s1 = gamma[c + 1] * rsqrtf(var[c + 1] + BN_EPS);
  float r0 = (h0 - mean[c])     * s0 + beta[c];
  float r1 = (h1 - mean[c + 1]) * s1 + beta[c + 1];
  u32 pack = (u32)f2bf(r0) | ((u32)f2bf(r1) << 16);
  *(u32*)(hbn + (size_t)wid * HH + c) = pack;
  u32 hp = (u32)f2bf(hv.x) | ((u32)f2bf(hv.y) << 16);
  *(u32*)(hxb + (size_t)wid * HH + c) = hp;
}

// ---------------- gates GEMM v8: full-k per wave, ZERO barriers, 2 waves/SIMD ----------------
// Round-11 lesson: the k-split structure (v5-v7) is pinned at ~70us by its
// per-chunk __syncthreads (vmcnt drain + LDS round-trip x12/block) regardless
// of occupancy. v8 removes the barrier entirely: each wave owns 16 h-cols x
// ALL 4 gates x FULL k=256 -> btile[4][8] = 128 VGPR. At 2 waves/SIMD the
// register budget is 256: btile 128 + acc 16 + a_cur/a_nxt 64 + cxv/addr ~25
// = ~230 fits. __launch_bounds__(256,2) enforces the cap. Block = 4 waves =
// 64 h-cols (hh = blockIdx.y), B loaded ONCE per persistent block, no LDS,
// no barriers, pure dataflow: next chunk's 8 A-frags + this chunk's cx
// prefetched before the 32 MFMAs. v2 (same structure, no prefetch, B reloaded
// every 3 chunks) = 86us; prefetch was worth ~2x on v6.
__global__ __launch_bounds__(256, 2) void gates_mfma8(
    const u16* __restrict__ hbn, const u16* __restrict__ hxb,
    const u16* __restrict__ wcat, const float* __restrict__ bsum,
    const float* __restrict__ cx, float* __restrict__ out, int N){
  int tid = threadIdx.x;
  int wave = tid >> 6, lane = tid & 63;
  int c = lane & 15, q = lane >> 4;
  int hh = blockIdx.y;                           // h-half [0,2)
  int ct = hh * 4 + wave;                        // col-tile [0,8)
  int hloc = ct * 16 + c;                        // h in [0,128)

  // resident B: 4 gates x 8 kk steps = 128 VGPR, loaded once
  const bf16x8* wsrc = (const bf16x8*)wcat;
  bf16x8 btile[4][8];
#pragma unroll
  for (int g = 0; g < 4; g++)
#pragma unroll
    for (int kk = 0; kk < 8; kk++)
      btile[g][kk] = wsrc[((size_t)((g * 8 + ct) * 8) + kk) * 64 + lane];

  float bi  = bsum[hloc];
  float bf_ = bsum[128 + hloc];
  float bg  = bsum[256 + hloc];
  float bo  = bsum[384 + hloc];
  const size_t NH = (size_t)N * HH;
  const int nchunk = N >> 4;                     // 3125 (N = 50000 = 3125*16)
  int chunk = blockIdx.x;

  // preload first chunk's A fragments (k half 1 from hbn, half 2 from hxb)
  bf16x8 a_cur[8];
  {
    const u16* ap0 = hbn + (size_t)((chunk << 4) + c) * 128 + q * 8;
    const u16* ap1 = hxb + (size_t)((chunk << 4) + c) * 128 + q * 8;
#pragma unroll
    for (int kk = 0; kk < 4; kk++){
      a_cur[kk]     = *(const bf16x8*)(ap0 + kk * 32);
      a_cur[4 + kk] = *(const bf16x8*)(ap1 + kk * 32);
    }
  }

  for (; chunk < nchunk; chunk += gridDim.x){
    int row0 = chunk << 4;
    // prefetch next chunk's A (in flight across all 32 MFMAs + epilogue)
    int nxt = chunk + gridDim.x;
    int prow = (nxt < nchunk) ? (nxt << 4) : 0;  // clamp: loads valid, unused
    const u16* pn0 = hbn + (size_t)(prow + c) * 128 + q * 8;
    const u16* pn1 = hxb + (size_t)(prow + c) * 128 + q * 8;
    bf16x8 a_nxt[8];
#pragma unroll
    for (int kk = 0; kk < 4; kk++){
      a_nxt[kk]     = *(const bf16x8*)(pn0 + kk * 32);
      a_nxt[4 + kk] = *(const bf16x8*)(pn1 + kk * 32);
    }
    // prefetch this chunk's cx
    float cxv[4];
#pragma unroll
    for (int j = 0; j < 4; j++)
      cxv[j] = cx[(size_t)(row0 + q * 4 + j) * HH + hloc];

    f32x4 acc[4];
#pragma unroll
    for (int g = 0; g < 4; g++) acc[g] = (f32x4){0.f, 0.f, 0.f, 0.f};
#pragma unroll
    for (int kk = 0; kk < 8; kk++){
#pragma unroll
      for (int g = 0; g < 4; g++)
        acc[g] = __builtin_amdgcn_mfma_f32_16x16x32_bf16(a_cur[kk], btile[g][kk], acc[g], 0, 0, 0);
    }
    // fused LSTM epilogue (all 4 gates register-local; no exchange needed)
#pragma unroll
    for (int j = 0; j < 4; j++){
      int r = row0 + q * 4 + j;
      float gi = acc[0][j] + bi;
      float gf = acc[1][j] + bf_;
      float gg = acc[2][j] + bg;
      float go = acc[3][j] + bo;
      float is = sigm(gi), fs = sigm(gf), gt = tanh_fast(gg), os = sigm(go);
      float cyv = cxv[j] * fs + is * gt;
      out[(size_t)r * HH + hloc]      = os * tanh_fast(cyv);
      out[NH + (size_t)r * HH + hloc] = cyv;
    }
#pragma unroll
    for (int kk = 0; kk < 8; kk++) a_cur[kk] = a_nxt[kk];
  }
}

// ---------------- launch ----------------

extern "C" void kernel_launch(void* const* d_in, const int* in_sizes, int n_in,
                              void* d_out, int out_size, void* d_ws, size_t ws_size,
                              hipStream_t stream){
  const float* x     = (const float*)d_in[0];
  const float* hx    = (const float*)d_in[1];
  const float* cx    = (const float*)d_in[2];
  const int*   esrc  = (const int*)d_in[3];
  const int*   edst  = (const int*)d_in[4];
  const float* ew    = (const float*)d_in[5];
  const float* gcn_w = (const float*)d_in[6];
  const float* bias  = (const float*)d_in[7];
  const float* x2hw  = (const float*)d_in[8];
  const float* x2hb  = (const float*)d_in[9];
  const float* h2hw  = (const float*)d_in[10];
  const float* h2hb  = (const float*)d_in[11];
  const float* bn_g  = (const float*)d_in[12];
  const float* bn_b  = (const float*)d_in[13];
  const float* bn_m  = (const float*)d_in[14];
  const float* bn_v  = (const float*)d_in[15];
  float* out = (float*)d_out;

  char* w = (char*)d_ws;
  u16* support = (u16*)w; w += (((size_t)NN * HH * 2) + 255) & ~(size_t)255;
  u16* hbn     = (u16*)w; w += (((size_t)NN * HH * 2) + 255) & ~(size_t)255;
  u16* hxb     = (u16*)w; w += (((size_t)NN * HH * 2) + 255) & ~(size_t)255;
  int* counts  = (int*)w; w += (((size_t)NN * 4) + 255) & ~(size_t)255;
  int* offs    = (int*)w; w += (((size_t)NN * 4) + 255) & ~(size_t)255;
  int* cursor  = (int*)w; w += (((size_t)NN * 4) + 255) & ~(size_t)255;
  int* bsums   = (int*)w; w += (((size_t)SCAN_NB * 4) + 255) & ~(size_t)255;
  int2* esw    = (int2*)w; w += (((size_t)NE * 8) + 255) & ~(size_t)255;
  u16* wcat    = (u16*)w; w += (((size_t)512 * 256 * 2) + 255) & ~(size_t)255;
  u16* wgcn    = (u16*)w; w += (((size_t)128 * 128 * 2) + 255) & ~(size_t)255;
  float* bsum  = (float*)w; w += (((size_t)512 * 4) + 255) & ~(size_t)255;

  hipMemsetAsync(counts, 0, (size_t)NN * 4, stream);
  fused_prep_hist<<<PREP_NB + HIST_NB, 256, 0, stream>>>(
      x2hw, h2hw, x2hb, h2hb, gcn_w, wcat, wgcn, bsum, edst, counts);
  scan_bsum<<<SCAN_NB, 256, 0, stream>>>(counts, bsums, NN);
  scan_final2<<<SCAN_NB, 256, 0, stream>>>(counts, bsums, offs, cursor, NN, SCAN_NB);
  fused_support_scatter<<<SUPP_NB + SCAT_NB, 256, 0, stream>>>(
      x, wgcn, support, esrc, edst, ew, cursor, esw, NN);
  agg_bn3<<<(NN + 3) / 4, 256, 0, stream>>>(support, esw, offs, counts,
                                            bias, bn_g, bn_b, bn_m, bn_v, hx, hbn, hxb, NN);
  gates_mfma8<<<dim3(512, 2), 256, 0, stream>>>(hbn, hxb, wcat, bsum, cx, out, NN);
}